// Round 3
// baseline (106.094 us; speedup 1.0000x reference)
//
#include <hip/hip_runtime.h>
#include <hip/hip_fp16.h>

// Deformable conv B=4 C=64 H=W=128 O=64 3x3 s1 p1 d1, DG=1.
// v11 = v10 minus the x-transpose prep kernel: dcn stages its 14x44 window
// directly from fp32 x (8 strided dword loads per slot, coalesced per
// channel-row; fp16-pack in-register; same ds_write_b128 octet layout).
// Kills the 2048-block prep dispatch + the 8MB xt HBM/L3 round-trip.
// prep shrinks to a 24-block wt convert. Round-2 sampling consolidated on
// wave 3 at full lane occupancy (was 25%-masked issue on all 4 waves).

#define B_  4
#define C_  64
#define H_  128
#define W_  128
#define O_  64
#define HO_ 128
#define WO_ 128
#define NCHUNK 8
#define NGW 12            // weight K-groups per chunk: 9 real taps + 3 zero
#define NT_ 32            // wo tile per block
#define NROW 2            // ho rows per block
#define NCOL 64           // NROW * NT_  (MFMA n dimension)
#define NTASK (9 * NCOL)  // 576 sampling tasks per chunk
#define SG  10            // sS groups per buffer: 9 taps + 1 zero pad
#define SBUF (SG * NCOL * 8)  // halves per buffer (5120 = 10 KB)
#define TR  14            // tile rows    (y in [ho-6, ho+8))
#define TC  44            // tile cols    (x in [woB-6, woB+38))
#define TSLOTS (TR * TC)  // 616 positions x 16 B
#define TBUF (TSLOTS * 8) // halves per tile buffer
#define HW_ (H_ * W_)

typedef _Float16 half8 __attribute__((ext_vector_type(8)));
typedef __attribute__((ext_vector_type(4))) float f32x4;
typedef __attribute__((ext_vector_type(16))) float f32x16;

union H8 { float4 v; __half2 h2[4]; half8 v8; };

// wt fp16 [(ch*12+g)*64+o]*8+e  (g<9: tap g, else 0). 24 blocks only.
__global__ __launch_bounds__(256)
void prep_wt(const float* __restrict__ w, __half* __restrict__ wt) {
    int t = blockIdx.x * 256 + threadIdx.x;   // (ch,g,o), 6144 total
    if (t >= NCHUNK * NGW * O_) return;
    int o  = t & 63;
    int g  = (t >> 6) % NGW;
    int ch = (t >> 6) / NGW;
    union { __half h[8]; float4 v; } pk;
#pragma unroll
    for (int e = 0; e < 8; ++e)
        pk.h[e] = (g < 9) ? __float2half_rn(w[(o * C_ + ch * 8 + e) * 9 + g])
                          : __half(0.0f);
    *(float4*)(wt + (size_t)t * 8) = pk.v;
}

__global__ __launch_bounds__(256, 4)
void dcn_mfma(const float* __restrict__ x, const float* __restrict__ off,
              const __half* __restrict__ wt, const float* __restrict__ bias,
              float* __restrict__ out) {
    __shared__ __align__(16) _Float16 sS[2 * SBUF];  // 20.0 KB sampled, dbuf
    __shared__ __align__(16) _Float16 sT[2 * TBUF];  // 19.25 KB window, dbuf

    const int tid = threadIdx.x;
    const int bid = blockIdx.x;              // (b, ho-pair, wo-quarter)
    const int w4  = bid & 3;
    const int hp  = (bid >> 2) & 63;
    const int b   = bid >> 8;
    const int ho  = hp << 1;                 // rows ho, ho+1
    const int woB = w4 * NT_;
    const int yb  = ho - 6;                  // tile origin (row)
    const int xb  = woB - 6;                 // tile origin (col)

    const float* xb_ = x + (size_t)b * C_ * HW_;   // batch image base

    // ---- bilinear metadata per task (k, row, wo_local): precomputed slot
    // addresses (tile-local if in-window, global if fallback) + fp16 weights ----
    // rounds 0,1: task = tid + r*256 (all lanes); round 2: 64 tasks on wave 3
    // (tid in [192,256), full lane occupancy).
    int a0_[3], a1_[3], nf_[3];
    __half2 ua2_[3], ub2_[3], va2_[3], vb2_[3];
#pragma unroll
    for (int r = 0; r < 3; ++r) {
        bool act = (r < 2) || (tid >= 192);
        if (act) {
            int task = (r < 2) ? (tid + r * 256) : (512 + (tid & 63));
            int k  = task >> 6;              // tap 0..8
            int n  = task & 63;              // row*32 + wo_local
            int wo = (n & 31) + woB;
            int hr = ho + (n >> 5);
            int ki = k / 3, kj = k - 3 * ki;
            float oy = off[(((b * 18) + 2 * k    ) * HO_ + hr) * WO_ + wo];
            float ox = off[(((b * 18) + 2 * k + 1) * HO_ + hr) * WO_ + wo];
            float py = (float)(hr - 1 + ki) + oy;
            float px = (float)(wo - 1 + kj) + ox;
            float y0f = floorf(py), x0f = floorf(px);
            int   y0 = (int)y0f,   x0 = (int)x0f;
            float ly = py - y0f,   lx = px - x0f;
            float hy = 1.f - ly,   hx = 1.f - lx;
            int y1 = y0 + 1, x1 = x0 + 1;
            float vy0 = (y0 >= 0 && y0 < H_) ? 1.f : 0.f;
            float vy1 = (y1 >= 0 && y1 < H_) ? 1.f : 0.f;
            float vx0 = (x0 >= 0 && x0 < W_) ? 1.f : 0.f;
            float vx1 = (x1 >= 0 && x1 < W_) ? 1.f : 0.f;
            int cy0 = min(max(y0, 0), H_ - 1), cy1 = min(max(y1, 0), H_ - 1);
            int ax  = min(max(x0, 0), W_ - 2);
            int cx0 = min(max(x0, 0), W_ - 1), cx1 = min(max(x1, 0), W_ - 1);
            float w00 = hy * hx * vy0 * vx0;
            float w01 = hy * lx * vy0 * vx1;
            float w10 = ly * hx * vy1 * vx0;
            float w11 = ly * lx * vy1 * vx1;
            float s0 = (cx0 != ax) ? 1.f : 0.f;
            float s1 = (cx1 != ax) ? 1.f : 0.f;
            int t0 = cy0 - yb, t1 = cy1 - yb, txx = ax - xb;
            int fb = ((unsigned)t0  > (TR - 1)) |
                     ((unsigned)t1  > (TR - 1)) |
                     ((unsigned)txx > (TC - 2));
            nf_[r] = !fb;
            a0_[r] = fb ? (cy0 * W_ + ax) : (t0 * TC + txx);
            a1_[r] = fb ? (cy1 * W_ + ax) : (t1 * TC + txx);
            ua2_[r] = __float2half2_rn(w00 * (1.f - s0) + w01 * (1.f - s1));
            ub2_[r] = __float2half2_rn(w00 * s0 + w01 * s1);
            va2_[r] = __float2half2_rn(w10 * (1.f - s0) + w11 * (1.f - s1));
            vb2_[r] = __float2half2_rn(w10 * s0 + w11 * s1);
        }
    }

    // ---- stage-slot global offsets (clamped): 616 slots, 2 full + 1 partial ----
    int gofs[3];
#pragma unroll
    for (int j = 0; j < 3; ++j) {
        int s  = tid + j * 256;
        int sc = (s < TSLOTS) ? s : (TSLOTS - 1);
        int rr = sc / TC, cc = sc - rr * TC;
        int yc = min(max(yb + rr, 0), H_ - 1);
        int xc = min(max(xb + cc, 0), W_ - 1);
        gofs[j] = yc * W_ + xc;
    }

    // zero pad group (group 9) in both sS buffers: 256 dwords each
    ((unsigned int*)&sS[9 * NCOL * 8])[tid]        = 0u;
    ((unsigned int*)&sS[SBUF + 9 * NCOL * 8])[tid] = 0u;

    // ---- window prefetch registers: 8 fp32 channels per owned slot ----
    float pfv[3][8];
    auto issue = [&](int ch) {
        const float* xc = xb_ + (size_t)(ch * 8) * HW_;
#pragma unroll
        for (int j = 0; j < 3; ++j) {
            if (j < 2 || tid < TSLOTS - 512) {
#pragma unroll
                for (int e = 0; e < 8; ++e)
                    pfv[j][e] = xc[(size_t)e * HW_ + gofs[j]];
            }
        }
    };
    auto tile_write = [&](int parity) {
        float4* tw = (float4*)(sT + parity * TBUF);
#pragma unroll
        for (int j = 0; j < 3; ++j) {
            if (j < 2 || tid < TSLOTS - 512) {
                H8 pk;
#pragma unroll
                for (int jj = 0; jj < 4; ++jj)
                    pk.h2[jj] = __floats2half2_rn(pfv[j][2 * jj], pfv[j][2 * jj + 1]);
                tw[tid + j * 256] = pk.v;
            }
        }
    };

    // ---- sample: LDS-window bilinear gather + fp16 blend -> sS[parity] ----
    auto sample = [&](int ch) {
        _Float16* buf = sS + (ch & 1) * SBUF;
        const float* xcg = xb_ + (size_t)(ch * 8) * HW_;
        const float4* tl = (const float4*)(sT + (ch & 1) * TBUF);
#pragma unroll
        for (int r = 0; r < 3; ++r) {
            bool act = (r < 2) || (tid >= 192);
            if (act) {
                int task = (r < 2) ? (tid + r * 256) : (512 + (tid & 63));
                int k = task >> 6;
                int n = task & 63;
                int a0 = a0_[r], a1 = a1_[r];
                H8 q00, q01, q10, q11;
                if (nf_[r]) {
                    q00.v = tl[a0];  q01.v = tl[a0 + 1];
                    q10.v = tl[a1];  q11.v = tl[a1 + 1];
                } else {   // exact fallback for |offset| beyond the window (~never)
#pragma unroll
                    for (int jj = 0; jj < 4; ++jj) {
                        int e0 = 2 * jj, e1 = 2 * jj + 1;
                        q00.h2[jj] = __floats2half2_rn(xcg[(size_t)e0 * HW_ + a0],
                                                       xcg[(size_t)e1 * HW_ + a0]);
                        q01.h2[jj] = __floats2half2_rn(xcg[(size_t)e0 * HW_ + a0 + 1],
                                                       xcg[(size_t)e1 * HW_ + a0 + 1]);
                        q10.h2[jj] = __floats2half2_rn(xcg[(size_t)e0 * HW_ + a1],
                                                       xcg[(size_t)e1 * HW_ + a1]);
                        q11.h2[jj] = __floats2half2_rn(xcg[(size_t)e0 * HW_ + a1 + 1],
                                                       xcg[(size_t)e1 * HW_ + a1 + 1]);
                    }
                }
                H8 s;
#pragma unroll
                for (int j = 0; j < 4; ++j) {
                    __half2 t0 = __hmul2(ua2_[r], q00.h2[j]);
                    t0 = __hfma2(ub2_[r], q01.h2[j], t0);
                    t0 = __hfma2(va2_[r], q10.h2[j], t0);
                    t0 = __hfma2(vb2_[r], q11.h2[j], t0);
                    s.h2[j] = t0;
                }
                *(half8*)&buf[(k * NCOL + n) * 8] = s.v8;
            }
        }
    };

    // ---- GEMM lane mapping: 2(o-half) x 2(ho-row) wave split, 32x32x16 MFMA ----
    const int lane = tid & 63;
    const int wv   = tid >> 6;
    const int ow   = wv & 1;       // o half  (32)
    const int nw   = wv >> 1;      // n half  (32 = one ho row)
    const int h2k  = lane >> 5;    // k-half within fragment
    const int l31  = lane & 31;

    f32x16 acc = {0.f, 0.f, 0.f, 0.f, 0.f, 0.f, 0.f, 0.f,
                  0.f, 0.f, 0.f, 0.f, 0.f, 0.f, 0.f, 0.f};

    auto mfma_chunk = [&](int ch) {
        const __half*   wc  = wt + (size_t)(ch * NGW) * O_ * 8;
        const _Float16* buf = sS + (ch & 1) * SBUF;
#pragma unroll
        for (int ks = 0; ks < 6; ++ks) {
            int g  = 2 * ks + h2k;               // 0..11 across lane halves
            int gb = (g < 9) ? g : 9;            // groups 9..11 -> zero pad
            half8 bfr = *(const half8*)&buf[(gb * NCOL + nw * 32 + l31) * 8];
            half8 afr = *(const half8*)(wc + (size_t)(g * O_ + ow * 32 + l31) * 8);
            acc = __builtin_amdgcn_mfma_f32_32x32x16_f16(afr, bfr, acc, 0, 0, 0);
        }
    };

    issue(0);
    tile_write(0);                             // waits vmcnt(issue 0)
    for (int ch = 0; ch < NCHUNK; ++ch) {
        __syncthreads();                       // sT[ch&1] ready; sS[(ch-1)&1] ready
        if (ch + 1 < NCHUNK) issue(ch + 1);    // loads in flight across the chunk
        sample(ch);                            // LDS gather -> sS[ch&1]
        if (ch > 0) mfma_chunk(ch - 1);        // reads sS[(ch-1)&1]
        if (ch + 1 < NCHUNK) tile_write((ch + 1) & 1);  // vmcnt wait overlapped
    }
    __syncthreads();
    mfma_chunk(NCHUNK - 1);

    // ---- epilogue: C/D col = lane&31 (n), row = (rg&3)+8*(rg>>2)+4*h2k (o) ----
    {
        int wo = woB + l31;
        size_t base = (((size_t)b * O_) * HO_ + ho + nw) * WO_ + wo;
#pragma unroll
        for (int rg = 0; rg < 16; ++rg) {
            int o = ow * 32 + (rg & 3) + 8 * (rg >> 2) + 4 * h2k;
            out[base + (size_t)o * HO_ * WO_] = acc[rg] + bias[o];
        }
    }
}

extern "C" void kernel_launch(void* const* d_in, const int* in_sizes, int n_in,
                              void* d_out, int out_size, void* d_ws, size_t ws_size,
                              hipStream_t stream) {
    const float* x    = (const float*)d_in[0];
    const float* off  = (const float*)d_in[1];
    const float* w    = (const float*)d_in[2];
    const float* bias = (const float*)d_in[3];
    float* out = (float*)d_out;

    __half* wt = (__half*)d_ws;                       // 98304 B

    hipLaunchKernelGGL(prep_wt, dim3(24), dim3(256), 0, stream, w, wt);
    hipLaunchKernelGGL(dcn_mfma, dim3(B_ * (HO_ / NROW) * (WO_ / NT_)), dim3(256), 0, stream,
                       x, off, wt, bias, out);
}

// Round 4
// 98.420 us; speedup vs baseline: 1.0780x; 1.0780x over previous
//
#include <hip/hip_runtime.h>
#include <hip/hip_fp16.h>

// Deformable conv B=4 C=64 H=W=128 O=64 3x3 s1 p1 d1, DG=1.
// v12 = v9 structure minus the sS relay stage: each lane bilinear-gathers its
// OWN MFMA B-octet (group g = ks*4+quad, col n = wv*16+l15) from the staged
// 16x48 window and feeds mfma_f32_16x16x32_f16 directly in registers.
// Wave owns an n-quarter (16 cols) x full O=64 (4 MFMAs/ks, acc 16 VGPR).
// Removes: sS double-buffer (20 KB LDS), sample->sS writes + frag re-reads,
// one barrier/chunk, the cross-wave handoff. Task count unchanged (576/chunk).
// Fake groups g>=9: broadcast-read slot 0 (free) x zero wt octets. v11 lesson:
// keep the xt fp16 pre-transpose (direct fp32 staging cost +8 us).

#define B_  4
#define C_  64
#define H_  128
#define W_  128
#define O_  64
#define HO_ 128
#define WO_ 128
#define NCHUNK 8
#define NGW 12            // wt K-groups per chunk: 9 real taps + 3 zero
#define NT_ 32            // wo tile per block
#define NROW 2            // ho rows per block
#define TR  16            // tile rows    (y in [ho-6, ho+10))
#define TC  48            // tile cols    (x in [woB-8, woB+40))
#define TSLOTS (TR * TC)  // 768 positions x 16 B
#define TBUF (TSLOTS * 8) // halves per tile buffer (12 KB)
#define HW_ (H_ * W_)

typedef _Float16 half8 __attribute__((ext_vector_type(8)));
typedef __attribute__((ext_vector_type(4))) float f32x4;

union H8 { float4 v; __half2 h2[4]; half8 v8; };

// Merged prep: blocks [0,2048) transpose+cvt x -> xt fp16 [B][CH=8][H][W][8ch];
// blocks [2048,2072) build wt fp16 [(ch*12+g)*64+o]*8+e  (g<9: tap g, else 0).
__global__ __launch_bounds__(256)
void prep(const float* __restrict__ x, const float* __restrict__ w,
          __half* __restrict__ xt, __half* __restrict__ wt) {
    const int tid = threadIdx.x;
    if (blockIdx.x < 2048) {
        int t = blockIdx.x * 256 + tid;          // (b,ch,y,x)
        int xc = t & 127;
        int y  = (t >> 7) & 127;
        int ch = (t >> 14) & 7;
        int b  = t >> 17;
        const float* xp = x + (((size_t)(b * C_ + ch * 8) * H_) + y) * W_ + xc;
        union { __half h[8]; float4 v; } pk;
#pragma unroll
        for (int e = 0; e < 8; ++e) pk.h[e] = __float2half_rn(xp[e * H_ * W_]);
        *(float4*)(xt + (size_t)t * 8) = pk.v;
    } else {
        int t = (blockIdx.x - 2048) * 256 + tid;  // (ch,g,o), 6144 total
        if (t >= NCHUNK * NGW * O_) return;
        int o  = t & 63;
        int g  = (t >> 6) % NGW;
        int ch = (t >> 6) / NGW;
        union { __half h[8]; float4 v; } pk;
#pragma unroll
        for (int e = 0; e < 8; ++e)
            pk.h[e] = (g < 9) ? __float2half_rn(w[(o * C_ + ch * 8 + e) * 9 + g])
                              : __half(0.0f);
        *(float4*)(wt + (size_t)t * 8) = pk.v;
    }
}

__global__ __launch_bounds__(256, 4)
void dcn_mfma(const __half* __restrict__ xt, const float* __restrict__ off,
              const __half* __restrict__ wt, const float* __restrict__ bias,
              float* __restrict__ out) {
    __shared__ __align__(16) _Float16 sT[2 * TBUF];  // 24 KB window, dbuf

    const int tid = threadIdx.x;
    const int bid = blockIdx.x;              // (b, ho-pair, wo-quarter)
    const int w4  = bid & 3;
    const int hp  = (bid >> 2) & 63;
    const int b   = bid >> 8;
    const int ho  = hp << 1;                 // rows ho, ho+1
    const int woB = w4 * NT_;
    const int yb  = ho - 6;                  // tile origin (row)
    const int xb  = woB - 8;                 // tile origin (col)

    const int lane = tid & 63;
    const int wv   = tid >> 6;
    const int quad = lane >> 4;
    const int l15  = lane & 15;
    const int n    = wv * 16 + l15;          // output col 0..63 (2 rows x 32 wo)
    const int hr   = ho + (n >> 5);
    const int wo   = woB + (n & 31);

    // ---- bilinear metadata: 3 tasks/lane, tap g = ks*4+quad at pixel n ----
    int a0_[3], a1_[3], nf_[3];
    __half2 ua2_[3], ub2_[3], va2_[3], vb2_[3];
#pragma unroll
    for (int ks = 0; ks < 3; ++ks) {
        int g = ks * 4 + quad;
        if (g < 9) {
            int ki = g / 3, kj = g - 3 * ki;
            float oy = off[(((b * 18) + 2 * g    ) * HO_ + hr) * WO_ + wo];
            float ox = off[(((b * 18) + 2 * g + 1) * HO_ + hr) * WO_ + wo];
            float py = (float)(hr - 1 + ki) + oy;
            float px = (float)(wo - 1 + kj) + ox;
            float y0f = floorf(py), x0f = floorf(px);
            int   y0 = (int)y0f,   x0 = (int)x0f;
            float ly = py - y0f,   lx = px - x0f;
            float hy = 1.f - ly,   hx = 1.f - lx;
            int y1 = y0 + 1, x1 = x0 + 1;
            float vy0 = (y0 >= 0 && y0 < H_) ? 1.f : 0.f;
            float vy1 = (y1 >= 0 && y1 < H_) ? 1.f : 0.f;
            float vx0 = (x0 >= 0 && x0 < W_) ? 1.f : 0.f;
            float vx1 = (x1 >= 0 && x1 < W_) ? 1.f : 0.f;
            int cy0 = min(max(y0, 0), H_ - 1), cy1 = min(max(y1, 0), H_ - 1);
            int ax  = min(max(x0, 0), W_ - 2);
            int cx0 = min(max(x0, 0), W_ - 1), cx1 = min(max(x1, 0), W_ - 1);
            float w00 = hy * hx * vy0 * vx0;
            float w01 = hy * lx * vy0 * vx1;
            float w10 = ly * hx * vy1 * vx0;
            float w11 = ly * lx * vy1 * vx1;
            float s0 = (cx0 != ax) ? 1.f : 0.f;
            float s1 = (cx1 != ax) ? 1.f : 0.f;
            int t0 = cy0 - yb, t1 = cy1 - yb, txx = ax - xb;
            int fb = ((unsigned)t0  > (TR - 1)) |
                     ((unsigned)t1  > (TR - 1)) |
                     ((unsigned)txx > (TC - 2));
            nf_[ks] = !fb;
            a0_[ks] = fb ? (cy0 * W_ + ax) : (t0 * TC + txx);
            a1_[ks] = fb ? (cy1 * W_ + ax) : (t1 * TC + txx);
            ua2_[ks] = __float2half2_rn(w00 * (1.f - s0) + w01 * (1.f - s1));
            ub2_[ks] = __float2half2_rn(w00 * s0 + w01 * s1);
            va2_[ks] = __float2half2_rn(w10 * (1.f - s0) + w11 * (1.f - s1));
            vb2_[ks] = __float2half2_rn(w10 * s0 + w11 * s1);
        } else {       // zero group: broadcast-read slot 0, weights 0, wt is 0 too
            nf_[ks] = 1; a0_[ks] = 0; a1_[ks] = 0;
            ua2_[ks] = ub2_[ks] = va2_[ks] = vb2_[ks] = __float2half2_rn(0.f);
        }
    }

    // ---- stage-slot global offsets (clamped): 768 slots = 3 per thread ----
    int gofs[3];
#pragma unroll
    for (int j = 0; j < 3; ++j) {
        int s  = tid + j * 256;
        int rr = s / TC, cc = s - rr * TC;
        int yc = min(max(yb + rr, 0), H_ - 1);
        int xc = min(max(xb + cc, 0), W_ - 1);
        gofs[j] = yc * W_ + xc;
    }

    // ---- window prefetch registers ----
    float4 pf0, pf1, pf2;
    auto issue = [&](int ch) {
        const float4* xc = (const float4*)(xt + ((size_t)(b * NCHUNK + ch)) * (HW_ * 8));
        pf0 = xc[gofs[0]];
        pf1 = xc[gofs[1]];
        pf2 = xc[gofs[2]];
    };
    auto tile_write = [&](int parity) {
        float4* tw = (float4*)(sT + parity * TBUF);
        tw[tid]       = pf0;
        tw[tid + 256] = pf1;
        tw[tid + 512] = pf2;
    };

    // ---- accumulators: wave = n-quarter (16 cols) x full O=64 ----
    f32x4 acc[4];
#pragma unroll
    for (int ot = 0; ot < 4; ++ot) acc[ot] = (f32x4){0.f, 0.f, 0.f, 0.f};

    // ---- fused gather+blend+MFMA per chunk ----
    auto compute = [&](int ch) {
        const float4* tl  = (const float4*)(sT + (ch & 1) * TBUF);
        const float4* xcg = (const float4*)(xt + ((size_t)(b * NCHUNK + ch)) * (HW_ * 8));
        const __half* wc  = wt + (size_t)(ch * NGW) * O_ * 8;
#pragma unroll
        for (int ks = 0; ks < 3; ++ks) {
            int g = ks * 4 + quad;
            H8 q00, q01, q10, q11;
            if (nf_[ks]) {
                int a0 = a0_[ks], a1 = a1_[ks];
                q00.v = tl[a0];  q01.v = tl[a0 + 1];
                q10.v = tl[a1];  q11.v = tl[a1 + 1];
            } else {   // exact fallback for |offset| beyond the window (~never)
                int a0 = a0_[ks], a1 = a1_[ks];
                q00.v = xcg[a0]; q01.v = xcg[a0 + 1];
                q10.v = xcg[a1]; q11.v = xcg[a1 + 1];
            }
            H8 s;
#pragma unroll
            for (int j = 0; j < 4; ++j) {
                __half2 t0 = __hmul2(ua2_[ks], q00.h2[j]);
                t0 = __hfma2(ub2_[ks], q01.h2[j], t0);
                t0 = __hfma2(va2_[ks], q10.h2[j], t0);
                t0 = __hfma2(vb2_[ks], q11.h2[j], t0);
                s.h2[j] = t0;
            }
#pragma unroll
            for (int ot = 0; ot < 4; ++ot) {
                half8 afr = *(const half8*)(wc + (size_t)(g * O_ + ot * 16 + l15) * 8);
                acc[ot] = __builtin_amdgcn_mfma_f32_16x16x32_f16(afr, s.v8, acc[ot], 0, 0, 0);
            }
        }
    };

    issue(0);
    tile_write(0);                             // waits vmcnt(issue 0)
    for (int ch = 0; ch < NCHUNK; ++ch) {
        __syncthreads();                       // sT[ch&1] ready for all waves
        if (ch + 1 < NCHUNK) issue(ch + 1);    // loads in flight across the chunk
        compute(ch);                           // gather own B-octets, MFMA direct
        if (ch + 1 < NCHUNK) tile_write((ch + 1) & 1);  // vmcnt wait overlapped
    }

    // ---- epilogue: C/D col = l15 (n-local), row = quad*4+rg (o-local) ----
    {
        int row = wv >> 1;                     // n>>5
        int woo = woB + (wv & 1) * 16 + l15;   // n&31
        size_t base = (((size_t)(b * O_)) * HO_ + ho + row) * WO_ + woo;
#pragma unroll
        for (int ot = 0; ot < 4; ++ot)
#pragma unroll
            for (int rg = 0; rg < 4; ++rg) {
                int o = ot * 16 + quad * 4 + rg;
                out[base + (size_t)o * HO_ * WO_] = acc[ot][rg] + bias[o];
            }
    }
}

extern "C" void kernel_launch(void* const* d_in, const int* in_sizes, int n_in,
                              void* d_out, int out_size, void* d_ws, size_t ws_size,
                              hipStream_t stream) {
    const float* x    = (const float*)d_in[0];
    const float* off  = (const float*)d_in[1];
    const float* w    = (const float*)d_in[2];
    const float* bias = (const float*)d_in[3];
    float* out = (float*)d_out;

    __half* wt = (__half*)d_ws;                       // 98304 B
    __half* xt = (__half*)((char*)d_ws + 262144);     // 8 MB

    hipLaunchKernelGGL(prep, dim3(2048 + 24), dim3(256), 0, stream, x, w, xt, wt);
    hipLaunchKernelGGL(dcn_mfma, dim3(B_ * (HO_ / NROW) * (WO_ / NT_)), dim3(256), 0, stream,
                       xt, off, wt, bias, out);
}

// Round 5
// 96.597 us; speedup vs baseline: 1.0983x; 1.0189x over previous
//
#include <hip/hip_runtime.h>
#include <hip/hip_fp16.h>

// Deformable conv B=4 C=64 H=W=128 O=64 3x3 s1 p1 d1, DG=1.
// v13 = v12 + (1) XCD-contiguous blockIdx swizzle (1024 = 8 XCDs x 128 blocks;
// each XCD gets a contiguous (b,ho) band -> staged xt window ~160 KB/chunk/XCD,
// L2-resident instead of cross-XCD L3 traffic) and (2) global_load_lds 16B
// staging of the window tile (direct HBM/L2->LDS DMA: kills the global->VGPR->
// ds_write round-trip, -12 pf VGPRs, dest = wave-uniform base + lane*16).
// v9-v12 lesson: relay/barrier/MFMA-shape all neutral -> staging path is what's left.

#define B_  4
#define C_  64
#define H_  128
#define W_  128
#define O_  64
#define HO_ 128
#define WO_ 128
#define NCHUNK 8
#define NGW 12            // wt K-groups per chunk: 9 real taps + 3 zero
#define NT_ 32            // wo tile per block
#define NROW 2            // ho rows per block
#define TR  16            // tile rows    (y in [ho-6, ho+10))
#define TC  48            // tile cols    (x in [woB-8, woB+40))
#define TSLOTS (TR * TC)  // 768 positions x 16 B = 3*256
#define TBUF (TSLOTS * 8) // halves per tile buffer (12 KB)
#define HW_ (H_ * W_)

typedef _Float16 half8 __attribute__((ext_vector_type(8)));
typedef __attribute__((ext_vector_type(4))) float f32x4;

union H8 { float4 v; __half2 h2[4]; half8 v8; };

// Merged prep: blocks [0,2048) transpose+cvt x -> xt fp16 [B][CH=8][H][W][8ch];
// blocks [2048,2072) build wt fp16 [(ch*12+g)*64+o]*8+e  (g<9: tap g, else 0).
__global__ __launch_bounds__(256)
void prep(const float* __restrict__ x, const float* __restrict__ w,
          __half* __restrict__ xt, __half* __restrict__ wt) {
    const int tid = threadIdx.x;
    if (blockIdx.x < 2048) {
        int t = blockIdx.x * 256 + tid;          // (b,ch,y,x)
        int xc = t & 127;
        int y  = (t >> 7) & 127;
        int ch = (t >> 14) & 7;
        int b  = t >> 17;
        const float* xp = x + (((size_t)(b * C_ + ch * 8) * H_) + y) * W_ + xc;
        union { __half h[8]; float4 v; } pk;
#pragma unroll
        for (int e = 0; e < 8; ++e) pk.h[e] = __float2half_rn(xp[e * H_ * W_]);
        *(float4*)(xt + (size_t)t * 8) = pk.v;
    } else {
        int t = (blockIdx.x - 2048) * 256 + tid;  // (ch,g,o), 6144 total
        if (t >= NCHUNK * NGW * O_) return;
        int o  = t & 63;
        int g  = (t >> 6) % NGW;
        int ch = (t >> 6) / NGW;
        union { __half h[8]; float4 v; } pk;
#pragma unroll
        for (int e = 0; e < 8; ++e)
            pk.h[e] = (g < 9) ? __float2half_rn(w[(o * C_ + ch * 8 + e) * 9 + g])
                              : __half(0.0f);
        *(float4*)(wt + (size_t)t * 8) = pk.v;
    }
}

__global__ __launch_bounds__(256, 4)
void dcn_mfma(const __half* __restrict__ xt, const float* __restrict__ off,
              const __half* __restrict__ wt, const float* __restrict__ bias,
              float* __restrict__ out) {
    __shared__ __align__(16) _Float16 sT[2 * TBUF];  // 24 KB window, dbuf

    const int tid = threadIdx.x;
    // XCD-contiguous swizzle: 1024 blocks = 8 XCDs x 128 contiguous ids (bijective).
    const int bid = (blockIdx.x & 7) * 128 + (blockIdx.x >> 3);
    const int w4  = bid & 3;
    const int hp  = (bid >> 2) & 63;
    const int b   = bid >> 8;
    const int ho  = hp << 1;                 // rows ho, ho+1
    const int woB = w4 * NT_;
    const int yb  = ho - 6;                  // tile origin (row)
    const int xb  = woB - 8;                 // tile origin (col)

    const int lane = tid & 63;
    const int wv   = tid >> 6;
    const int quad = lane >> 4;
    const int l15  = lane & 15;
    const int n    = wv * 16 + l15;          // output col 0..63 (2 rows x 32 wo)
    const int hr   = ho + (n >> 5);
    const int wo   = woB + (n & 31);

    // ---- bilinear metadata: 3 tasks/lane, tap g = ks*4+quad at pixel n ----
    int a0_[3], a1_[3], nf_[3];
    __half2 ua2_[3], ub2_[3], va2_[3], vb2_[3];
#pragma unroll
    for (int ks = 0; ks < 3; ++ks) {
        int g = ks * 4 + quad;
        if (g < 9) {
            int ki = g / 3, kj = g - 3 * ki;
            float oy = off[(((b * 18) + 2 * g    ) * HO_ + hr) * WO_ + wo];
            float ox = off[(((b * 18) + 2 * g + 1) * HO_ + hr) * WO_ + wo];
            float py = (float)(hr - 1 + ki) + oy;
            float px = (float)(wo - 1 + kj) + ox;
            float y0f = floorf(py), x0f = floorf(px);
            int   y0 = (int)y0f,   x0 = (int)x0f;
            float ly = py - y0f,   lx = px - x0f;
            float hy = 1.f - ly,   hx = 1.f - lx;
            int y1 = y0 + 1, x1 = x0 + 1;
            float vy0 = (y0 >= 0 && y0 < H_) ? 1.f : 0.f;
            float vy1 = (y1 >= 0 && y1 < H_) ? 1.f : 0.f;
            float vx0 = (x0 >= 0 && x0 < W_) ? 1.f : 0.f;
            float vx1 = (x1 >= 0 && x1 < W_) ? 1.f : 0.f;
            int cy0 = min(max(y0, 0), H_ - 1), cy1 = min(max(y1, 0), H_ - 1);
            int ax  = min(max(x0, 0), W_ - 2);
            int cx0 = min(max(x0, 0), W_ - 1), cx1 = min(max(x1, 0), W_ - 1);
            float w00 = hy * hx * vy0 * vx0;
            float w01 = hy * lx * vy0 * vx1;
            float w10 = ly * hx * vy1 * vx0;
            float w11 = ly * lx * vy1 * vx1;
            float s0 = (cx0 != ax) ? 1.f : 0.f;
            float s1 = (cx1 != ax) ? 1.f : 0.f;
            int t0 = cy0 - yb, t1 = cy1 - yb, txx = ax - xb;
            int fb = ((unsigned)t0  > (TR - 1)) |
                     ((unsigned)t1  > (TR - 1)) |
                     ((unsigned)txx > (TC - 2));
            nf_[ks] = !fb;
            a0_[ks] = fb ? (cy0 * W_ + ax) : (t0 * TC + txx);
            a1_[ks] = fb ? (cy1 * W_ + ax) : (t1 * TC + txx);
            ua2_[ks] = __float2half2_rn(w00 * (1.f - s0) + w01 * (1.f - s1));
            ub2_[ks] = __float2half2_rn(w00 * s0 + w01 * s1);
            va2_[ks] = __float2half2_rn(w10 * (1.f - s0) + w11 * (1.f - s1));
            vb2_[ks] = __float2half2_rn(w10 * s0 + w11 * s1);
        } else {       // zero group: broadcast-read slot 0, weights 0, wt is 0 too
            nf_[ks] = 1; a0_[ks] = 0; a1_[ks] = 0;
            ua2_[ks] = ub2_[ks] = va2_[ks] = vb2_[ks] = __float2half2_rn(0.f);
        }
    }

    // ---- stage-slot global offsets (clamped): 768 slots = 3 per thread ----
    int gofs[3];
#pragma unroll
    for (int j = 0; j < 3; ++j) {
        int s  = tid + j * 256;
        int rr = s / TC, cc = s - rr * TC;
        int yc = min(max(yb + rr, 0), H_ - 1);
        int xc = min(max(xb + cc, 0), W_ - 1);
        gofs[j] = yc * W_ + xc;
    }

    // ---- async window staging: global_load_lds 16B/lane, linear LDS dest ----
    // dest slot = wv*64 + j*256 + lane  ->  wave-uniform base + lane*16 (m104 ok).
    auto stage = [&](int ch, int parity) {
        const char* xc = (const char*)(xt + ((size_t)(b * NCHUNK + ch)) * (HW_ * 8));
        char* lb = (char*)sT + (size_t)parity * (TBUF * 2) + (size_t)(tid & ~63) * 16;
#pragma unroll
        for (int j = 0; j < 3; ++j)
            __builtin_amdgcn_global_load_lds(
                (const __attribute__((address_space(1))) unsigned int*)(xc + (size_t)gofs[j] * 16),
                (__attribute__((address_space(3))) unsigned int*)(lb + j * 4096),
                16, 0, 0);
    };

    // ---- accumulators: wave = n-quarter (16 cols) x full O=64 ----
    f32x4 acc[4];
#pragma unroll
    for (int ot = 0; ot < 4; ++ot) acc[ot] = (f32x4){0.f, 0.f, 0.f, 0.f};

    // ---- fused gather+blend+MFMA per chunk ----
    auto compute = [&](int ch) {
        const float4* tl  = (const float4*)(sT + (ch & 1) * TBUF);
        const float4* xcg = (const float4*)(xt + ((size_t)(b * NCHUNK + ch)) * (HW_ * 8));
        const __half* wc  = wt + (size_t)(ch * NGW) * O_ * 8;
#pragma unroll
        for (int ks = 0; ks < 3; ++ks) {
            int g = ks * 4 + quad;
            H8 q00, q01, q10, q11;
            if (nf_[ks]) {
                int a0 = a0_[ks], a1 = a1_[ks];
                q00.v = tl[a0];  q01.v = tl[a0 + 1];
                q10.v = tl[a1];  q11.v = tl[a1 + 1];
            } else {   // exact fallback for |offset| beyond the window (~never)
                int a0 = a0_[ks], a1 = a1_[ks];
                q00.v = xcg[a0]; q01.v = xcg[a0 + 1];
                q10.v = xcg[a1]; q11.v = xcg[a1 + 1];
            }
            H8 s;
#pragma unroll
            for (int j = 0; j < 4; ++j) {
                __half2 t0 = __hmul2(ua2_[ks], q00.h2[j]);
                t0 = __hfma2(ub2_[ks], q01.h2[j], t0);
                t0 = __hfma2(va2_[ks], q10.h2[j], t0);
                t0 = __hfma2(vb2_[ks], q11.h2[j], t0);
                s.h2[j] = t0;
            }
#pragma unroll
            for (int ot = 0; ot < 4; ++ot) {
                half8 afr = *(const half8*)(wc + (size_t)(g * O_ + ot * 16 + l15) * 8);
                acc[ot] = __builtin_amdgcn_mfma_f32_16x16x32_f16(afr, s.v8, acc[ot], 0, 0, 0);
            }
        }
    };

    stage(0, 0);
    __syncthreads();                           // drains vmcnt: sT[0] ready
    for (int ch = 0; ch < NCHUNK; ++ch) {
        if (ch + 1 < NCHUNK) stage(ch + 1, (ch + 1) & 1);  // DMA in flight over compute
        compute(ch);                           // gather own B-octets, MFMA direct
        __syncthreads();                       // drains stage; sT[ch&1] free, next ready
    }

    // ---- epilogue: C/D col = l15 (n-local), row = quad*4+rg (o-local) ----
    {
        int row = wv >> 1;                     // n>>5
        int woo = woB + (wv & 1) * 16 + l15;   // n&31
        size_t base = (((size_t)(b * O_)) * HO_ + ho + row) * WO_ + woo;
#pragma unroll
        for (int ot = 0; ot < 4; ++ot)
#pragma unroll
            for (int rg = 0; rg < 4; ++rg) {
                int o = ot * 16 + quad * 4 + rg;
                out[base + (size_t)o * HO_ * WO_] = acc[ot][rg] + bias[o];
            }
    }
}

extern "C" void kernel_launch(void* const* d_in, const int* in_sizes, int n_in,
                              void* d_out, int out_size, void* d_ws, size_t ws_size,
                              hipStream_t stream) {
    const float* x    = (const float*)d_in[0];
    const float* off  = (const float*)d_in[1];
    const float* w    = (const float*)d_in[2];
    const float* bias = (const float*)d_in[3];
    float* out = (float*)d_out;

    __half* wt = (__half*)d_ws;                       // 98304 B
    __half* xt = (__half*)((char*)d_ws + 262144);     // 8 MB

    hipLaunchKernelGGL(prep, dim3(2048 + 24), dim3(256), 0, stream, x, w, xt, wt);
    hipLaunchKernelGGL(dcn_mfma, dim3(B_ * (HO_ / NROW) * (WO_ / NT_)), dim3(256), 0, stream,
                       xt, off, wt, bias, out);
}